// Round 4
// baseline (108.487 us; speedup 1.0000x reference)
//
#include <hip/hip_runtime.h>

typedef __bf16 bf16;
typedef __bf16 bf16x8 __attribute__((ext_vector_type(8)));
typedef float f32x4 __attribute__((ext_vector_type(4)));

// LDS x-slab: [ld 4][lh 4 (pad 5)][w 32 (pad 33)][ci 32 (pad 40)]  (bf16)
// ci-row = 40 bf16 = 80 B (16B-aligned); all strides 16B-aligned for b128.
#define W_STRIDE 40
#define H_STRIDE (33 * W_STRIDE)   // 1320
#define D_STRIDE (5 * H_STRIDE)    // 6600
#define XS_ELEMS (4 * D_STRIDE)    // 26400 bf16 = 52800 B

__global__ __launch_bounds__(256) void fused_mfma_kernel(
    const float* __restrict__ x, const float* __restrict__ W,
    const float* __restrict__ b, float* __restrict__ out) {
  __shared__ __align__(16) bf16 xs[XS_ELEMS];
  __shared__ float red[10][2][16];

  const int t = threadIdx.x;
  const int lane = t & 63;
  const int wv = t >> 6;  // 0..3
  const int co = lane & 15;
  const int quad = lane >> 4;

  // XCD swizzle: n = blk&7 -> same-n adjacent-oh blocks land on one XCD (L2 reuse)
  const int blk = blockIdx.x;      // 800
  const int n = blk & 7;
  const int odoh = blk >> 3;       // 0..99
  const int od = odoh / 10;
  const int oh = odoh % 10;

  // ---- stage x slab: x[n][ci][3od+ld][3oh+lh][w 0..31] -> xs[ld][lh][w][ci]
  // float4 along w: 8 lanes x 16 B = 128 B coalesced; 16 loads + 8 b128 writes/thread
  {
    const float* xn = x + (size_t)n * (32 * 32768) + (3 * od) * 1024 + (3 * oh) * 32;
#pragma unroll
    for (int it = 0; it < 2; ++it) {
      const int f = it * 256 + t;  // 0..511
      const int wg = f & 7;        // group of 4 w's
      const int cig = (f >> 3) & 3;
      const int lh = (f >> 5) & 3;
      const int ld = f >> 7;
      const float* g = xn + (size_t)(cig * 8) * 32768 + ld * 1024 + lh * 32 + wg * 4;
      f32x4 v[8];
#pragma unroll
      for (int j = 0; j < 8; ++j) v[j] = *(const f32x4*)(g + (size_t)j * 32768);
      bf16* base = &xs[ld * D_STRIDE + lh * H_STRIDE + (wg * 4) * W_STRIDE + cig * 8];
#pragma unroll
      for (int k = 0; k < 4; ++k) {
        bf16x8 pk;
#pragma unroll
        for (int j = 0; j < 8; ++j) pk[j] = (bf16)v[j][k];
        *(bf16x8*)(base + k * W_STRIDE) = pk;
      }
    }
  }

  // ---- B fragments gathered directly from W (fp32, tap-contiguous rows, L2-hot)
  // bfrag[tap][j] = W[((quad*8+j)*16 + co)*27 + tap]
  bf16x8 bfrag[27];
  {
#pragma unroll
    for (int j = 0; j < 8; ++j) {
      const float* wr = W + ((quad * 8 + j) * 16 + co) * 27;
#pragma unroll
      for (int tap = 0; tap < 27; ++tap) bfrag[tap][j] = (bf16)wr[tap];
    }
  }
  __syncthreads();

  // ---- 20 tasks = 10 windows x 2 M-tiles; wave-uniform tile
  const int tile = wv >> 1;  // 0,0,1,1
  int pos = tile * 16 + (lane & 15);
  if (pos > 26) pos = 26;  // tile-1 garbage rows; excluded from max below
  const int md = pos / 9;
  const int mh = (pos / 3) % 3;
  const int mw = pos % 3;

  for (int i = 0; i < 5; ++i) {
    const int w10 = (wv & 1) * 5 + i;  // window ow
    const bf16* ap = xs + md * D_STRIDE + mh * H_STRIDE + (3 * w10 + mw) * W_STRIDE + quad * 8;

    // 8 distinct A fragments: input offsets (dd,dh,dw) in {0,1}^3
    bf16x8 af[8];
#pragma unroll
    for (int dd = 0; dd < 2; ++dd)
#pragma unroll
      for (int dh = 0; dh < 2; ++dh)
#pragma unroll
        for (int dw = 0; dw < 2; ++dw)
          af[dd * 4 + dh * 2 + dw] =
              *(const bf16x8*)(ap + dd * D_STRIDE + dh * H_STRIDE + dw * W_STRIDE);

    float tmax = -3.4e38f;
#pragma unroll
    for (int pd = 0; pd < 2; ++pd)
#pragma unroll
      for (int ph = 0; ph < 2; ++ph)
#pragma unroll
        for (int pw = 0; pw < 2; ++pw) {
          f32x4 acc = {0.f, 0.f, 0.f, 0.f};
#pragma unroll
          for (int td = 0; td <= pd; ++td)
#pragma unroll
            for (int th = 0; th <= ph; ++th)
#pragma unroll
              for (int tw = 0; tw <= pw; ++tw) {
                const int kd = pd ? (td ? 2 : 0) : 1;
                const int kh = ph ? (th ? 2 : 0) : 1;
                const int kw = pw ? (tw ? 2 : 0) : 1;
                const int ai = ((kd == 0) ? 4 : 0) + ((kh == 0) ? 2 : 0) + ((kw == 0) ? 1 : 0);
                acc = __builtin_amdgcn_mfma_f32_16x16x32_bf16(
                    af[ai], bfrag[kd * 9 + kh * 3 + kw], acc, 0, 0, 0);
              }
          // C/D: col = lane&15 (co), row = quad*4 + reg
          if (tile == 0) {
#pragma unroll
            for (int r = 0; r < 4; ++r) tmax = fmaxf(tmax, acc[r]);
          } else {
#pragma unroll
            for (int r = 0; r < 4; ++r)
              if (16 + quad * 4 + r < 27) tmax = fmaxf(tmax, acc[r]);
          }
        }

    tmax = fmaxf(tmax, __shfl_xor(tmax, 16, 64));
    tmax = fmaxf(tmax, __shfl_xor(tmax, 32, 64));
    if (quad == 0) red[w10][tile][co] = tmax;
  }
  __syncthreads();

  // ---- combine tiles, add bias, sum over co, store (10 outputs/block)
  if (t < 160) {
    const int w10 = t >> 4;
    const int c = t & 15;
    float v = fmaxf(red[w10][0][c], red[w10][1][c]) + b[c];
    v += __shfl_xor(v, 1, 64);
    v += __shfl_xor(v, 2, 64);
    v += __shfl_xor(v, 4, 64);
    v += __shfl_xor(v, 8, 64);
    if (c == 0) out[n * 1000 + od * 100 + oh * 10 + w10] = v;
  }
}

extern "C" void kernel_launch(void* const* d_in, const int* in_sizes, int n_in,
                              void* d_out, int out_size, void* d_ws, size_t ws_size,
                              hipStream_t stream) {
  const float* x = (const float*)d_in[0];  // 8*32*32*32*32 fp32
  const float* W = (const float*)d_in[1];  // 32*16*27 fp32
  const float* b = (const float*)d_in[2];  // 16 fp32
  float* out = (float*)d_out;              // 8000 fp32
  fused_mfma_kernel<<<dim3(800), dim3(256), 0, stream>>>(x, W, b, out);
}

// Round 5
// 91.414 us; speedup vs baseline: 1.1868x; 1.1868x over previous
//
#include <hip/hip_runtime.h>

typedef __bf16 bf16;
typedef __bf16 bf16x8 __attribute__((ext_vector_type(8)));
typedef float f32x4 __attribute__((ext_vector_type(4)));

// LDS x-slab: [ld 4][lh 4 (pad 5)][w 32 (pad 33)][ci 32 (pad 40)]  (bf16)
// ci-row = 40 bf16 = 80 B (16B-aligned); all strides 16B-aligned for b128.
#define W_STRIDE 40
#define H_STRIDE (33 * W_STRIDE)   // 1320
#define D_STRIDE (5 * H_STRIDE)    // 6600
#define XS_ELEMS (4 * D_STRIDE)    // 26400 bf16 = 52800 B

// W (32ci,16co,27tap fp32) -> B-fragment order bf16 in d_ws:
// o = ((tap*4 + quad)*16 + co)*8 + j, ci = quad*8 + j
__global__ void transpose_w_kernel(const float* __restrict__ W, bf16* __restrict__ Wt) {
  int o = blockIdx.x * 256 + threadIdx.x;
  if (o < 27 * 512) {
    int j = o & 7, co = (o >> 3) & 15, q = (o >> 7) & 3, tap = o >> 9;
    Wt[o] = (bf16)W[((q * 8 + j) * 16 + co) * 27 + tap];
  }
}

__global__ __launch_bounds__(256) void fused_mfma_kernel(
    const float* __restrict__ x, const bf16* __restrict__ Wt,
    const float* __restrict__ b, float* __restrict__ out) {
  __shared__ __align__(16) bf16 xs[XS_ELEMS];
  __shared__ float red[10][2][16];

  const int t = threadIdx.x;
  const int lane = t & 63;
  const int wv = t >> 6;  // 0..3
  const int co = lane & 15;
  const int quad = lane >> 4;

  // XCD swizzle: n = blk&7 -> all blocks of one n land on one XCD (x[n] = 4.2 MB
  // fits that XCD's 4 MiB L2; round-4 FETCH_SIZE 15.7 MB vs 52 MB requested).
  const int blk = blockIdx.x;      // 800
  const int n = blk & 7;
  const int odoh = blk >> 3;       // 0..99
  const int od = odoh / 10;
  const int oh = odoh % 10;

  // ---- B fragments: 27 coalesced dwordx4 loads from Wt (L2-hot), issued first
  bf16x8 bfrag[27];
  {
    const bf16x8* wp = (const bf16x8*)Wt;
#pragma unroll
    for (int tap = 0; tap < 27; ++tap)
      bfrag[tap] = wp[(tap * 4 + quad) * 16 + co];
  }

  // ---- stage x slab: x[n][ci][3od+ld][3oh+lh][w 0..31] -> xs[ld][lh][w][ci]
  // float4 along w: 16 dwordx4 loads + 8 b128 LDS writes per thread
  {
    const float* xn = x + (size_t)n * (32 * 32768) + (3 * od) * 1024 + (3 * oh) * 32;
#pragma unroll
    for (int it = 0; it < 2; ++it) {
      const int f = it * 256 + t;  // 0..511
      const int wg = f & 7;        // group of 4 w's
      const int cig = (f >> 3) & 3;
      const int lh = (f >> 5) & 3;
      const int ld = f >> 7;
      const float* g = xn + (size_t)(cig * 8) * 32768 + ld * 1024 + lh * 32 + wg * 4;
      f32x4 v[8];
#pragma unroll
      for (int j = 0; j < 8; ++j) v[j] = *(const f32x4*)(g + (size_t)j * 32768);
      bf16* base = &xs[ld * D_STRIDE + lh * H_STRIDE + (wg * 4) * W_STRIDE + cig * 8];
#pragma unroll
      for (int k = 0; k < 4; ++k) {
        bf16x8 pk;
#pragma unroll
        for (int j = 0; j < 8; ++j) pk[j] = (bf16)v[j][k];
        *(bf16x8*)(base + k * W_STRIDE) = pk;
      }
    }
  }
  __syncthreads();

  // ---- 20 tasks = 10 windows x 2 M-tiles; wave-uniform tile
  const int tile = wv >> 1;  // 0,0,1,1
  int pos = tile * 16 + (lane & 15);
  if (pos > 26) pos = 26;  // tile-1 garbage rows; excluded from max below
  const int md = pos / 9;
  const int mh = (pos / 3) % 3;
  const int mw = pos % 3;

  for (int i = 0; i < 5; ++i) {
    const int w10 = (wv & 1) * 5 + i;  // window ow
    const bf16* ap = xs + md * D_STRIDE + mh * H_STRIDE + (3 * w10 + mw) * W_STRIDE + quad * 8;

    // 8 distinct A fragments: input offsets (dd,dh,dw) in {0,1}^3
    bf16x8 af[8];
#pragma unroll
    for (int dd = 0; dd < 2; ++dd)
#pragma unroll
      for (int dh = 0; dh < 2; ++dh)
#pragma unroll
        for (int dw = 0; dw < 2; ++dw)
          af[dd * 4 + dh * 2 + dw] =
              *(const bf16x8*)(ap + dd * D_STRIDE + dh * H_STRIDE + dw * W_STRIDE);

    float tmax = -3.4e38f;
#pragma unroll
    for (int pd = 0; pd < 2; ++pd)
#pragma unroll
      for (int ph = 0; ph < 2; ++ph)
#pragma unroll
        for (int pw = 0; pw < 2; ++pw) {
          f32x4 acc = {0.f, 0.f, 0.f, 0.f};
#pragma unroll
          for (int td = 0; td <= pd; ++td)
#pragma unroll
            for (int th = 0; th <= ph; ++th)
#pragma unroll
              for (int tw = 0; tw <= pw; ++tw) {
                const int kd = pd ? (td ? 2 : 0) : 1;
                const int kh = ph ? (th ? 2 : 0) : 1;
                const int kw = pw ? (tw ? 2 : 0) : 1;
                const int ai = ((kd == 0) ? 4 : 0) + ((kh == 0) ? 2 : 0) + ((kw == 0) ? 1 : 0);
                acc = __builtin_amdgcn_mfma_f32_16x16x32_bf16(
                    af[ai], bfrag[kd * 9 + kh * 3 + kw], acc, 0, 0, 0);
              }
          // C/D: col = lane&15 (co), row = quad*4 + reg
          if (tile == 0) {
#pragma unroll
            for (int r = 0; r < 4; ++r) tmax = fmaxf(tmax, acc[r]);
          } else {
#pragma unroll
            for (int r = 0; r < 4; ++r)
              if (16 + quad * 4 + r < 27) tmax = fmaxf(tmax, acc[r]);
          }
        }

    tmax = fmaxf(tmax, __shfl_xor(tmax, 16, 64));
    tmax = fmaxf(tmax, __shfl_xor(tmax, 32, 64));
    if (quad == 0) red[w10][tile][co] = tmax;
  }
  __syncthreads();

  // ---- combine tiles, add bias, sum over co, store (10 outputs/block)
  if (t < 160) {
    const int w10 = t >> 4;
    const int c = t & 15;
    float v = fmaxf(red[w10][0][c], red[w10][1][c]) + b[c];
    v += __shfl_xor(v, 1, 64);
    v += __shfl_xor(v, 2, 64);
    v += __shfl_xor(v, 4, 64);
    v += __shfl_xor(v, 8, 64);
    if (c == 0) out[n * 1000 + od * 100 + oh * 10 + w10] = v;
  }
}

extern "C" void kernel_launch(void* const* d_in, const int* in_sizes, int n_in,
                              void* d_out, int out_size, void* d_ws, size_t ws_size,
                              hipStream_t stream) {
  const float* x = (const float*)d_in[0];  // 8*32*32*32*32 fp32
  const float* W = (const float*)d_in[1];  // 32*16*27 fp32
  const float* b = (const float*)d_in[2];  // 16 fp32
  float* out = (float*)d_out;              // 8000 fp32
  bf16* Wt = (bf16*)d_ws;                  // 13824 bf16 = 27648 B scratch

  transpose_w_kernel<<<dim3(54), dim3(256), 0, stream>>>(W, Wt);
  fused_mfma_kernel<<<dim3(800), dim3(256), 0, stream>>>(x, Wt, b, out);
}